// Round 8
// baseline (287.104 us; speedup 1.0000x reference)
//
#include <hip/hip_runtime.h>
#include <hip/hip_bf16.h>
#include <stdint.h>

typedef __attribute__((ext_vector_type(8))) short bf16x8;
typedef __attribute__((ext_vector_type(4))) float f32x4;

// ---- bf16 pack via native v_cvt_pk_bf16_f32 (RNE) ----
__device__ __forceinline__ bf16x8 pack2(float4 a, float4 b) {
    union { bf16x8 v; __hip_bfloat162 h[4]; } r;
    r.h[0] = __float22bfloat162_rn(make_float2(a.x, a.y));
    r.h[1] = __float22bfloat162_rn(make_float2(a.z, a.w));
    r.h[2] = __float22bfloat162_rn(make_float2(b.x, b.y));
    r.h[3] = __float22bfloat162_rn(make_float2(b.z, b.w));
    return r.v;
}
__device__ __forceinline__ bf16x8 addpack(bf16x8 ib, float4 a, float4 b) {
    union { bf16x8 v; __hip_bfloat162 h[4]; } s; s.v = ib;
    float2 f0 = __bfloat1622float2(s.h[0]);
    float2 f1 = __bfloat1622float2(s.h[1]);
    float2 f2 = __bfloat1622float2(s.h[2]);
    float2 f3 = __bfloat1622float2(s.h[3]);
    union { bf16x8 v; __hip_bfloat162 h[4]; } r;
    r.h[0] = __float22bfloat162_rn(make_float2(f0.x + a.x, f0.y + a.y));
    r.h[1] = __float22bfloat162_rn(make_float2(f1.x + a.z, f1.y + a.w));
    r.h[2] = __float22bfloat162_rn(make_float2(f2.x + b.x, f2.y + b.y));
    r.h[3] = __float22bfloat162_rn(make_float2(f3.x + b.z, f3.y + b.w));
    return r.v;
}
__device__ __forceinline__ float tanh_fast(float x) {
    float e = __expf(2.0f * x);
    return 1.0f - 2.0f / (e + 1.0f);
}
#define MFMA16(a, b, c) __builtin_amdgcn_mfma_f32_16x16x32_bf16((a), (b), (c), 0, 0, 0)

// =========================================================================
// Kernel 1 (tiny prep, 9 blocks): Wq -> bf16 B-frag chunks [c][n] in ws
// (read by inline-q from global); bk' = bk + Wk @ attr.
// =========================================================================
__global__ void finerec_prep(
    const float* __restrict__ attr,
    const float* __restrict__ Wq, const float* __restrict__ Wk,
    const float* __restrict__ bk,
    float* __restrict__ bkp_ws, short* __restrict__ wfq_ws)
{
    if (blockIdx.x == 8) {   // bk' = bk + Wk @ attr
        int n = threadIdx.x;
        if (n < 128) {
            const float* wr = Wk + n * 128;
            float s = bk[n];
            for (int k = 0; k < 128; k += 4) {
                float4 w4 = *(const float4*)(wr + k);
                float4 a4 = *(const float4*)(attr + k);
                s += w4.x * a4.x + w4.y * a4.y + w4.z * a4.z + w4.w * a4.w;
            }
            bkp_ws[n] = s;
        }
        return;
    }
    const int g = blockIdx.x * 256 + threadIdx.x;   // 0..2047
    const int c = g >> 7, n = g & 127;
    const float* src = Wq + n * 128 + c * 8;
    ((bf16x8*)wfq_ws)[(c << 7) + n] = pack2(*(const float4*)src, *(const float4*)(src + 4));
}

// =========================================================================
// Kernel 2 (main): HALF-USER jobs (32 rows each), one job per wave.
// 1024-thr blocks, launch_bounds(1024,4) -> 64-VGPR cap (empirical 256/arg2),
// LDS 73.5 KB -> 2 blocks/CU -> 32 waves/CU. Wk/Wv converted f32->bf16 into
// LDS per block; q inline per job (Wq frags from ws via L1). Results combined
// across the user's two jobs with atomicAdd into zeroed out.
// =========================================================================
__global__ __launch_bounds__(1024, 4) void finerec_main(
    const float* __restrict__ item_table, const float* __restrict__ opin_table,
    const float* __restrict__ user_emb,
    const float* __restrict__ bq, const float* __restrict__ bv,
    const float* __restrict__ Wk, const float* __restrict__ Wv,
    const int* __restrict__ item_seqs, const int* __restrict__ opin_seqs,
    const float* __restrict__ bkp_ws, const short* __restrict__ wfq_ws,
    float* __restrict__ out, int U, int L)
{
    __shared__ __align__(16) short wlds[32768];   // Wk (2048 16B chunks) + Wv (2048), XOR-swizzled
    __shared__ float q_lds[16 * 128];             // per-wave q row
    __shared__ float bq_lds[128], bkp_lds[128], bv_lds[128];

    const int tid = threadIdx.x;
    const int wv = tid >> 6, lane = tid & 63, l15 = lane & 15, quad = lane >> 4;

    // ---- convert Wk/Wv f32 -> bf16 frag chunks in LDS (4 chunks/thread) ----
    bf16x8* wldsv = (bf16x8*)wlds;
#pragma unroll
    for (int i = 0; i < 4; ++i) {
        const int id = i * 1024 + tid;            // 0..4095
        const int mat = id >> 11, rem = id & 2047, r = rem >> 4, cc = rem & 15;
        const float* src = (mat ? Wv : Wk) + r * 128 + cc * 8;
        wldsv[(mat << 11) + (r << 4) + (cc ^ (r & 15))] =
            pack2(*(const float4*)src, *(const float4*)(src + 4));
    }
    if (tid < 128)      bq_lds[tid]        = bq[tid];
    else if (tid < 256) bkp_lds[tid - 128] = bkp_ws[tid - 128];
    else if (tid < 384) bv_lds[tid - 256]  = bv[tid - 256];
    __syncthreads();   // the ONLY block barrier

    const int job = blockIdx.x * 16 + wv;
    if (job >= 2 * U) return;   // wave-uniform, after the barrier
    const int u  = job >> 1;
    const int rb = (job & 1) * 32;   // this job covers rows rb..rb+31

    // ---- this job's indices (lanes 0..31 hold rows rb..rb+31) ----
    int vi = 0, vo = 0;
    const int row = rb + lane;
    if (lane < 32 && row < L) { vi = item_seqs[u * L + row]; vo = opin_seqs[u * L + row]; }
    const unsigned long long mb = __ballot(vi > 0);   // bit l = mask of local row l

    // ---- inline q = tanh(user @ Wq^T + bq): user row as A row 0 ----
    {
        const float* up = user_emb + (size_t)u * 128 + quad * 8;
        const bf16x8* wfq = (const bf16x8*)wfq_ws;
        bf16x8 uq[4];
#pragma unroll
        for (int ks = 0; ks < 4; ++ks) {
            bf16x8 z = {0, 0, 0, 0, 0, 0, 0, 0};
            uq[ks] = (l15 == 0)
                ? pack2(*(const float4*)(up + ks * 32), *(const float4*)(up + ks * 32 + 4))
                : z;
        }
#pragma unroll 1
        for (int nt = 0; nt < 8; ++nt) {
            const int n = nt * 16 + l15;
            f32x4 cq = {0, 0, 0, 0};
#pragma unroll
            for (int ks = 0; ks < 4; ++ks)
                cq = MFMA16(uq[ks], wfq[((ks * 4 + quad) << 7) + n], cq);
            if (lane < 16) q_lds[wv * 128 + nt * 16 + lane] = tanh_fast(cq[0] + bq_lds[nt * 16 + lane]);
        }
    }

    // ---- gather item rows, two 16-row groups ----
    const int idx0 = __shfl(vi, l15);
    const int idx1 = __shfl(vi, 16 + l15);
    const float* p0 = item_table + (size_t)idx0 * 128 + quad * 8;
    const float* p1 = item_table + (size_t)idx1 * 128 + quad * 8;
    bf16x8 a0[4], a1[4];   // A-frags: row = lane&15, k = quad*8+j (+32*ks)
#pragma unroll
    for (int ks = 0; ks < 4; ++ks) {
        a0[ks] = pack2(*(const float4*)(p0 + ks * 32), *(const float4*)(p0 + ks * 32 + 4));
        a1[ks] = pack2(*(const float4*)(p1 + ks * 32), *(const float4*)(p1 + ks * 32 + 4));
    }
    // ---- K pass (attr folded into bk'); rolled nt ----
    float w0[4] = {0, 0, 0, 0}, w1[4] = {0, 0, 0, 0};
#pragma unroll 1
    for (int nt = 0; nt < 8; ++nt) {
        const int n = nt * 16 + l15;
        f32x4 c0 = {0, 0, 0, 0}, c1 = {0, 0, 0, 0};
#pragma unroll
        for (int ks = 0; ks < 4; ++ks) {
            bf16x8 wf = wldsv[(n << 4) + ((ks * 4 + quad) ^ (n & 15))];
            c0 = MFMA16(a0[ks], wf, c0);
            c1 = MFMA16(a1[ks], wf, c1);
        }
        const float qv  = q_lds[wv * 128 + n];
        const float bkv = bkp_lds[n];
#pragma unroll
        for (int r = 0; r < 4; ++r) {
            w0[r] += qv * tanh_fast(c0[r] + bkv);
            w1[r] += qv * tanh_fast(c1[r] + bkv);
        }
    }
    // ---- w: reduce over 16 cols within quad + padding mask ----
#pragma unroll
    for (int r = 0; r < 4; ++r) {
        float t0 = w0[r], t1 = w1[r];
        t0 += __shfl_xor(t0, 1); t0 += __shfl_xor(t0, 2);
        t0 += __shfl_xor(t0, 4); t0 += __shfl_xor(t0, 8);
        t1 += __shfl_xor(t1, 1); t1 += __shfl_xor(t1, 2);
        t1 += __shfl_xor(t1, 4); t1 += __shfl_xor(t1, 8);
        w0[r] = ((mb >> (quad * 4 + r)) & 1ull)      ? t0 : 0.0f;   // local row quad*4+r
        w1[r] = ((mb >> (16 + quad * 4 + r)) & 1ull) ? t1 : 0.0f;   // local row 16+quad*4+r
    }
    // ---- v_in = item + opin (reuse item frags, no re-gather) ----
    const int od0 = __shfl(vo, l15);
    const int od1 = __shfl(vo, 16 + l15);
    const float* o0p = opin_table + (size_t)od0 * 128 + quad * 8;
    const float* o1p = opin_table + (size_t)od1 * 128 + quad * 8;
#pragma unroll
    for (int ks = 0; ks < 4; ++ks) {
        a0[ks] = addpack(a0[ks], *(const float4*)(o0p + ks * 32), *(const float4*)(o0p + ks * 32 + 4));
        a1[ks] = addpack(a1[ks], *(const float4*)(o1p + ks * 32), *(const float4*)(o1p + ks * 32 + 4));
    }
    // ---- V pass + weighted aggregation; rolled nt, select-accumulate ----
    float s0 = 0.0f, s1 = 0.0f;   // this lane's 2 output columns
#pragma unroll 1
    for (int nt = 0; nt < 8; ++nt) {
        const int n = nt * 16 + l15;
        f32x4 c0 = {0, 0, 0, 0}, c1 = {0, 0, 0, 0};
#pragma unroll
        for (int ks = 0; ks < 4; ++ks) {
            bf16x8 wf = wldsv[2048 + (n << 4) + ((ks * 4 + quad) ^ (n & 15))];
            c0 = MFMA16(a0[ks], wf, c0);
            c1 = MFMA16(a1[ks], wf, c1);
        }
        const float bvv = bv_lds[n];
        float acc = 0.0f;
#pragma unroll
        for (int r = 0; r < 4; ++r) {
            acc += w0[r] * tanh_fast(c0[r] + bvv);
            acc += w1[r] * tanh_fast(c1[r] + bvv);
        }
        acc += __shfl_xor(acc, 16);   // sum the 4 row-quads
        acc += __shfl_xor(acc, 32);   // -> col sum over this job's 32 rows
        const bool mine = (quad == (nt >> 1));
        s0 += (mine && !(nt & 1)) ? acc : 0.0f;
        s1 += (mine &&  (nt & 1)) ? acc : 0.0f;
    }
    // ---- combine the user's two half-jobs ----
    atomicAdd(out + u * 128 + quad * 32 + l15, s0);        // col = (2*quad)*16 + l15
    atomicAdd(out + u * 128 + quad * 32 + 16 + l15, s1);   // col = (2*quad+1)*16 + l15
}

extern "C" void kernel_launch(void* const* d_in, const int* in_sizes, int n_in,
                              void* d_out, int out_size, void* d_ws, size_t ws_size,
                              hipStream_t stream) {
    const float* item_table = (const float*)d_in[0];
    const float* opin_table = (const float*)d_in[1];
    const float* user_emb   = (const float*)d_in[2];
    const float* attr       = (const float*)d_in[3];
    const float* Wq = (const float*)d_in[4];
    const float* bq = (const float*)d_in[5];
    const float* Wk = (const float*)d_in[6];
    const float* bk = (const float*)d_in[7];
    const float* Wv = (const float*)d_in[8];
    const float* bv = (const float*)d_in[9];
    const int* item_seqs = (const int*)d_in[10];
    const int* opin_seqs = (const int*)d_in[11];
    float* out = (float*)d_out;

    const int U = in_sizes[2] / 128;      // 10000
    const int L = in_sizes[10] / U;       // 50

    short* wfq_ws = (short*)d_ws;                       // 2048 x 16B bf16 chunks (Wq frags)
    float* bkp_ws = (float*)((char*)d_ws + 2048 * 16);  // [128] f32

    hipMemsetAsync(out, 0, (size_t)U * 128 * sizeof(float), stream);
    finerec_prep<<<9, 256, 0, stream>>>(attr, Wq, Wk, bk, bkp_ws, wfq_ws);

    const int grid = (2 * U + 15) / 16;   // half-user jobs, 16 per block
    finerec_main<<<grid, 1024, 0, stream>>>(
        item_table, opin_table, user_emb, bq, bv, Wk, Wv,
        item_seqs, opin_seqs, bkp_ws, wfq_ws, out, U, L);
}

// Round 9
// 237.942 us; speedup vs baseline: 1.2066x; 1.2066x over previous
//
#include <hip/hip_runtime.h>
#include <hip/hip_bf16.h>
#include <stdint.h>

typedef __attribute__((ext_vector_type(8))) short bf16x8;
typedef __attribute__((ext_vector_type(4))) float f32x4;

// ---- bf16 pack via native v_cvt_pk_bf16_f32 (RNE) ----
__device__ __forceinline__ bf16x8 pack2(float4 a, float4 b) {
    union { bf16x8 v; __hip_bfloat162 h[4]; } r;
    r.h[0] = __float22bfloat162_rn(make_float2(a.x, a.y));
    r.h[1] = __float22bfloat162_rn(make_float2(a.z, a.w));
    r.h[2] = __float22bfloat162_rn(make_float2(b.x, b.y));
    r.h[3] = __float22bfloat162_rn(make_float2(b.z, b.w));
    return r.v;
}
__device__ __forceinline__ bf16x8 addpack(bf16x8 ib, float4 a, float4 b) {
    union { bf16x8 v; __hip_bfloat162 h[4]; } s; s.v = ib;
    float2 f0 = __bfloat1622float2(s.h[0]);
    float2 f1 = __bfloat1622float2(s.h[1]);
    float2 f2 = __bfloat1622float2(s.h[2]);
    float2 f3 = __bfloat1622float2(s.h[3]);
    union { bf16x8 v; __hip_bfloat162 h[4]; } r;
    r.h[0] = __float22bfloat162_rn(make_float2(f0.x + a.x, f0.y + a.y));
    r.h[1] = __float22bfloat162_rn(make_float2(f1.x + a.z, f1.y + a.w));
    r.h[2] = __float22bfloat162_rn(make_float2(f2.x + b.x, f2.y + b.y));
    r.h[3] = __float22bfloat162_rn(make_float2(f3.x + b.z, f3.y + b.w));
    return r.v;
}
__device__ __forceinline__ float tanh_fast(float x) {
    float e = __expf(2.0f * x);
    return 1.0f - 2.0f / (e + 1.0f);
}
#define MFMA16(a, b, c) __builtin_amdgcn_mfma_f32_16x16x32_bf16((a), (b), (c), 0, 0, 0)

// =========================================================================
// Kernel 1 (prep): q = tanh(user @ Wq^T + bq) -> q_ws ;
//                  bk' = bk + Wk@attr -> bkp_ws ;
//                  Wk,Wv -> bf16 XOR-swizzled fragment chunks -> wf_ws
// (verbatim R5 structure — known-good)
// =========================================================================
__global__ void finerec_prep(
    const float* __restrict__ user_emb, const float* __restrict__ attr,
    const float* __restrict__ Wq, const float* __restrict__ bq,
    const float* __restrict__ Wk, const float* __restrict__ bk,
    const float* __restrict__ Wv,
    float* __restrict__ q_ws, float* __restrict__ bkp_ws,
    short* __restrict__ wf_ws, int U)
{
    if (blockIdx.x >= gridDim.x - 8) {           // ---- weight cast: 8 blocks x 512 chunks
        const int bi = blockIdx.x - (gridDim.x - 8);
#pragma unroll
        for (int t = 0; t < 2; ++t) {
            const int g = bi * 512 + t * 256 + threadIdx.x;   // 0..4095
            const int mat = g >> 11, gg = g & 2047, r = gg >> 4, c = gg & 15;
            const float* src = (mat ? Wv : Wk) + r * 128 + c * 8;
            ((bf16x8*)wf_ws)[(mat << 11) + (r << 4) + (c ^ (r & 15))] =
                pack2(*(const float4*)src, *(const float4*)(src + 4));
        }
        return;
    }
    if (blockIdx.x == gridDim.x - 9) {           // ---- bias fold: bk' = bk + Wk @ attr
        int n = threadIdx.x;
        if (n < 128) {
            const float* wr = Wk + n * 128;
            float s = bk[n];
            for (int k = 0; k < 128; k += 4) {
                float4 w4 = *(const float4*)(wr + k);
                float4 a4 = *(const float4*)(attr + k);
                s += w4.x * a4.x + w4.y * a4.y + w4.z * a4.z + w4.w * a4.w;
            }
            bkp_ws[n] = s;
        }
        return;
    }
    // ---- q: 64 users per block (16 per wave) ----
    const int tid = threadIdx.x, wv = tid >> 6, lane = tid & 63;
    const int l15 = lane & 15, quad = lane >> 4;
    const int u0 = (blockIdx.x * 4 + wv) * 16;
    int ur = u0 + l15; if (ur >= U) ur = U - 1;
    const float* up = user_emb + (size_t)ur * 128 + quad * 8;
    bf16x8 af[4];
#pragma unroll
    for (int ks = 0; ks < 4; ++ks)
        af[ks] = pack2(*(const float4*)(up + ks * 32), *(const float4*)(up + ks * 32 + 4));
#pragma unroll
    for (int nt = 0; nt < 8; ++nt) {
        const int n = nt * 16 + l15;
        const float* wp = Wq + n * 128 + quad * 8;
        f32x4 acc = {0, 0, 0, 0};
#pragma unroll
        for (int ks = 0; ks < 4; ++ks) {
            bf16x8 bf = pack2(*(const float4*)(wp + ks * 32), *(const float4*)(wp + ks * 32 + 4));
            acc = MFMA16(af[ks], bf, acc);
        }
        const float bqv = bq[n];
#pragma unroll
        for (int r = 0; r < 4; ++r) {            // C: col = lane&15, row = quad*4+r
            int row = u0 + quad * 4 + r;
            if (row < U) q_ws[row * 128 + nt * 16 + l15] = tanh_fast(acc[r] + bqv);
        }
    }
}

// =========================================================================
// Kernel 2 (main): persistent 512 blocks x 1024 thr, launch_bounds(1024,4)
// -> 64-VGPR cap (empirical: cap = 256/arg2), LDS 73 KB -> 2 blocks/CU
// -> 32 waves/CU. Weights staged into LDS ONCE per block (straight 16B
// copies of pre-swizzled frags). Wave-stride loop over QUARTER-USER jobs
// (16-row MFMA groups, 40000 jobs / 8192 waves = 4.88 -> 97.6% balance).
// q from prep's q_ws. Results combined via atomicAdd into zeroed out.
// =========================================================================
__global__ __launch_bounds__(1024, 4) void finerec_main(
    const float* __restrict__ item_table, const float* __restrict__ opin_table,
    const float* __restrict__ bv,
    const int* __restrict__ item_seqs, const int* __restrict__ opin_seqs,
    const float* __restrict__ q_ws, const float* __restrict__ bkp_ws,
    const short* __restrict__ wf_ws,
    float* __restrict__ out, int U, int L)
{
    __shared__ __align__(16) short wlds[32768];   // Wk (2048 16B chunks) + Wv (2048), XOR-swizzled
    __shared__ float q_lds[16 * 128];             // per-wave q row
    __shared__ float bkp_lds[128], bv_lds[128];

    const int tid = threadIdx.x;
    const int wv = tid >> 6, lane = tid & 63, l15 = lane & 15, quad = lane >> 4;

    // ---- stage pre-swizzled weights: straight 16B copies, 4/thread ----
    const bf16x8* wsrc = (const bf16x8*)wf_ws;
    bf16x8* wldsv = (bf16x8*)wlds;
#pragma unroll
    for (int i = 0; i < 4; ++i)
        wldsv[i * 1024 + tid] = wsrc[i * 1024 + tid];
    if (tid < 128)      bkp_lds[tid]       = bkp_ws[tid];
    else if (tid < 256) bv_lds[tid - 128]  = bv[tid - 128];
    __syncthreads();   // the ONLY block barrier

    const int nwaves = gridDim.x * 16;
    const int njobs  = 4 * U;

#pragma unroll 1
    for (int job = blockIdx.x * 16 + wv; job < njobs; job += nwaves) {
        const int u  = job >> 2;
        const int rb = (job & 3) * 16;   // rows rb..rb+15 of user u

        // ---- indices: lanes 0..15 hold this group's rows ----
        int vi = 0, vo = 0;
        if (lane < 16 && rb + lane < L) {
            vi = item_seqs[u * L + rb + lane];
            vo = opin_seqs[u * L + rb + lane];
        }
        const unsigned long long mb = __ballot(vi > 0);   // bits 0..15 = row mask

        // ---- stage this job's q row (intra-wave RAW, lgkmcnt-ordered) ----
        q_lds[wv * 128 + lane]      = q_ws[u * 128 + lane];
        q_lds[wv * 128 + 64 + lane] = q_ws[u * 128 + 64 + lane];

        // ---- gather item rows -> A-frags (row = l15, k = quad*8+j +32ks) ----
        const int idx = __shfl(vi, l15);
        const float* p = item_table + (size_t)idx * 128 + quad * 8;
        bf16x8 a[4];
#pragma unroll
        for (int ks = 0; ks < 4; ++ks)
            a[ks] = pack2(*(const float4*)(p + ks * 32), *(const float4*)(p + ks * 32 + 4));

        // ---- K pass (attr folded into bk'); rolled nt ----
        float w[4] = {0, 0, 0, 0};
#pragma unroll 1
        for (int nt = 0; nt < 8; ++nt) {
            const int n = nt * 16 + l15;
            f32x4 c = {0, 0, 0, 0};
#pragma unroll
            for (int ks = 0; ks < 4; ++ks)
                c = MFMA16(a[ks], wldsv[(n << 4) + ((ks * 4 + quad) ^ (n & 15))], c);
            const float qv  = q_lds[wv * 128 + n];
            const float bkv = bkp_lds[n];
#pragma unroll
            for (int r = 0; r < 4; ++r)
                w[r] += qv * tanh_fast(c[r] + bkv);
        }
        // ---- w: reduce over 16 cols within quad + padding mask ----
#pragma unroll
        for (int r = 0; r < 4; ++r) {
            float t = w[r];
            t += __shfl_xor(t, 1); t += __shfl_xor(t, 2);
            t += __shfl_xor(t, 4); t += __shfl_xor(t, 8);
            w[r] = ((mb >> (quad * 4 + r)) & 1ull) ? t : 0.0f;   // local row quad*4+r
        }
        // ---- v_in = item + opin (reuse item frags, no re-gather) ----
        const int od = __shfl(vo, l15);
        const float* op = opin_table + (size_t)od * 128 + quad * 8;
#pragma unroll
        for (int ks = 0; ks < 4; ++ks)
            a[ks] = addpack(a[ks], *(const float4*)(op + ks * 32), *(const float4*)(op + ks * 32 + 4));

        // ---- V pass + weighted aggregation; rolled nt, select-accumulate ----
        float s0 = 0.0f, s1 = 0.0f;
#pragma unroll 1
        for (int nt = 0; nt < 8; ++nt) {
            const int n = nt * 16 + l15;
            f32x4 c = {0, 0, 0, 0};
#pragma unroll
            for (int ks = 0; ks < 4; ++ks)
                c = MFMA16(a[ks], wldsv[2048 + (n << 4) + ((ks * 4 + quad) ^ (n & 15))], c);
            const float bvv = bv_lds[n];
            float acc = 0.0f;
#pragma unroll
            for (int r = 0; r < 4; ++r)
                acc += w[r] * tanh_fast(c[r] + bvv);
            acc += __shfl_xor(acc, 16);   // sum the 4 row-quads
            acc += __shfl_xor(acc, 32);   // -> col sum over this group's 16 rows
            const bool mine = (quad == (nt >> 1));
            s0 += (mine && !(nt & 1)) ? acc : 0.0f;
            s1 += (mine &&  (nt & 1)) ? acc : 0.0f;
        }
        // ---- combine the user's four quarter-jobs ----
        atomicAdd(out + u * 128 + quad * 32 + l15, s0);        // col = (2*quad)*16 + l15
        atomicAdd(out + u * 128 + quad * 32 + 16 + l15, s1);   // col = (2*quad+1)*16 + l15
    }
}

extern "C" void kernel_launch(void* const* d_in, const int* in_sizes, int n_in,
                              void* d_out, int out_size, void* d_ws, size_t ws_size,
                              hipStream_t stream) {
    const float* item_table = (const float*)d_in[0];
    const float* opin_table = (const float*)d_in[1];
    const float* user_emb   = (const float*)d_in[2];
    const float* attr       = (const float*)d_in[3];
    const float* Wq = (const float*)d_in[4];
    const float* bq = (const float*)d_in[5];
    const float* Wk = (const float*)d_in[6];
    const float* bk = (const float*)d_in[7];
    const float* Wv = (const float*)d_in[8];
    const float* bv = (const float*)d_in[9];
    const int* item_seqs = (const int*)d_in[10];
    const int* opin_seqs = (const int*)d_in[11];
    float* out = (float*)d_out;

    const int U = in_sizes[2] / 128;      // 10000
    const int L = in_sizes[10] / U;       // 50

    float* q_ws   = (float*)d_ws;                    // [U,128] f32
    float* bkp_ws = q_ws + (size_t)U * 128;          // [128] f32
    short* wf_ws  = (short*)(bkp_ws + 128);          // [4096*8] bf16 chunks

    hipMemsetAsync(out, 0, (size_t)U * 128 * sizeof(float), stream);

    const int qb = (U + 63) / 64;
    finerec_prep<<<qb + 1 + 8, 256, 0, stream>>>(
        user_emb, attr, Wq, bq, Wk, bk, Wv, q_ws, bkp_ws, wf_ws, U);

    finerec_main<<<512, 1024, 0, stream>>>(
        item_table, opin_table, bv, item_seqs, opin_seqs,
        q_ws, bkp_ws, wf_ws, out, U, L);
}

// Round 10
// 186.138 us; speedup vs baseline: 1.5424x; 1.2783x over previous
//
#include <hip/hip_runtime.h>
#include <hip/hip_bf16.h>
#include <stdint.h>

typedef __attribute__((ext_vector_type(8))) short bf16x8;
typedef __attribute__((ext_vector_type(4))) float f32x4;

#define S_2LOG2E 2.8853900817779268f   // 2*log2(e): tanh(x)=1-2/(2^(x*S)+1)

#if __has_builtin(__builtin_amdgcn_exp2f)
#define EXP2F(x) __builtin_amdgcn_exp2f(x)
#else
#define EXP2F(x) __expf((x) * 0.6931471805599453f)
#endif
#if __has_builtin(__builtin_amdgcn_rcpf)
#define RCPF(x) __builtin_amdgcn_rcpf(x)
#else
#define RCPF(x) (1.0f / (x))
#endif

// tanh given pre-scaled argument z = S*(x) : returns tanh(x)
__device__ __forceinline__ float tanh_z(float z) {
    float e = EXP2F(z);
    float r = RCPF(e + 1.0f);
    return fmaf(-2.0f, r, 1.0f);
}
__device__ __forceinline__ float tanh_fast(float x) {   // prep only
    float e = __expf(2.0f * x);
    return 1.0f - 2.0f / (e + 1.0f);
}

// ---- bf16 pack via native v_cvt_pk_bf16_f32 (RNE) ----
__device__ __forceinline__ bf16x8 pack2(float4 a, float4 b) {
    union { bf16x8 v; __hip_bfloat162 h[4]; } r;
    r.h[0] = __float22bfloat162_rn(make_float2(a.x, a.y));
    r.h[1] = __float22bfloat162_rn(make_float2(a.z, a.w));
    r.h[2] = __float22bfloat162_rn(make_float2(b.x, b.y));
    r.h[3] = __float22bfloat162_rn(make_float2(b.z, b.w));
    return r.v;
}
#define MFMA16(a, b, c) __builtin_amdgcn_mfma_f32_16x16x32_bf16((a), (b), (c), 0, 0, 0)

// =========================================================================
// Kernel 1 (prep), grid sections by blockIdx:
//  [0,qb)        q = tanh(user @ Wq^T + bq) -> q_ws        (R9-verbatim)
//  qb            bkz = S*(bk + Wk@attr), bvz = S*bv
//  (qb, qb+8]    Wk,Wv -> bf16 XOR-swizzled frag chunks -> wf_ws
//  (qb+8, qb+48] zero out (atomic target)
//  rest          item/opin tables -> bf16 chunks (optional, 224 blocks)
// =========================================================================
__global__ void finerec_prep(
    const float* __restrict__ user_emb, const float* __restrict__ attr,
    const float* __restrict__ Wq, const float* __restrict__ bq,
    const float* __restrict__ Wk, const float* __restrict__ bk,
    const float* __restrict__ Wv, const float* __restrict__ bv,
    const float* __restrict__ item_table, const float* __restrict__ opin_table,
    float* __restrict__ q_ws, float* __restrict__ bkz_ws, float* __restrict__ bvz_ws,
    short* __restrict__ wf_ws, short* __restrict__ itb, short* __restrict__ opb,
    float* __restrict__ out, int U, int n_item, int n_opi, int qb)
{
    const int bx = blockIdx.x, tid = threadIdx.x;
    if (bx >= qb + 49) {                     // ---- table cast to bf16 chunks ----
        const int gid = (bx - qb - 49) * 256 + tid;
        const int stride = 224 * 256;
        const int tci = n_item * 16, tc = (n_item + n_opi) * 16;
        for (int c = gid; c < tc; c += stride) {
            if (c < tci) {
                const float* src = item_table + (size_t)c * 8;
                ((bf16x8*)itb)[c] = pack2(*(const float4*)src, *(const float4*)(src + 4));
            } else {
                const float* src = opin_table + (size_t)(c - tci) * 8;
                ((bf16x8*)opb)[c - tci] = pack2(*(const float4*)src, *(const float4*)(src + 4));
            }
        }
        return;
    }
    if (bx >= qb + 9) {                      // ---- zero the atomic output ----
        const int gid = (bx - qb - 9) * 256 + tid;
        float4 z = {0.0f, 0.0f, 0.0f, 0.0f};
        for (int i = gid; i < U * 32; i += 40 * 256) ((float4*)out)[i] = z;
        return;
    }
    if (bx >= qb + 1) {                      // ---- weight cast: 8 blocks ----
        const int bi = bx - qb - 1;
#pragma unroll
        for (int t = 0; t < 2; ++t) {
            const int g = bi * 512 + t * 256 + tid;           // 0..4095
            const int mat = g >> 11, gg = g & 2047, r = gg >> 4, c = gg & 15;
            const float* src = (mat ? Wv : Wk) + r * 128 + c * 8;
            ((bf16x8*)wf_ws)[(mat << 11) + (r << 4) + (c ^ (r & 15))] =
                pack2(*(const float4*)src, *(const float4*)(src + 4));
        }
        return;
    }
    if (bx == qb) {                          // ---- pre-scaled biases ----
        if (tid < 128) {
            const float* wr = Wk + tid * 128;
            float s = bk[tid];
            for (int k = 0; k < 128; k += 4) {
                float4 w4 = *(const float4*)(wr + k);
                float4 a4 = *(const float4*)(attr + k);
                s += w4.x * a4.x + w4.y * a4.y + w4.z * a4.z + w4.w * a4.w;
            }
            bkz_ws[tid] = s * S_2LOG2E;
        } else if (tid < 256) {
            bvz_ws[tid - 128] = bv[tid - 128] * S_2LOG2E;
        }
        return;
    }
    // ---- q: 64 users per block (16 per wave) ----
    const int wv = tid >> 6, lane = tid & 63;
    const int l15 = lane & 15, quad = lane >> 4;
    const int u0 = (bx * 4 + wv) * 16;
    int ur = u0 + l15; if (ur >= U) ur = U - 1;
    const float* up = user_emb + (size_t)ur * 128 + quad * 8;
    bf16x8 af[4];
#pragma unroll
    for (int ks = 0; ks < 4; ++ks)
        af[ks] = pack2(*(const float4*)(up + ks * 32), *(const float4*)(up + ks * 32 + 4));
#pragma unroll
    for (int nt = 0; nt < 8; ++nt) {
        const int n = nt * 16 + l15;
        const float* wp = Wq + n * 128 + quad * 8;
        f32x4 acc = {0, 0, 0, 0};
#pragma unroll
        for (int ks = 0; ks < 4; ++ks) {
            bf16x8 bf = pack2(*(const float4*)(wp + ks * 32), *(const float4*)(wp + ks * 32 + 4));
            acc = MFMA16(af[ks], bf, acc);
        }
        const float bqv = bq[n];
#pragma unroll
        for (int r = 0; r < 4; ++r) {
            int row = u0 + quad * 4 + r;
            if (row < U) q_ws[row * 128 + nt * 16 + l15] = tanh_fast(acc[r] + bqv);
        }
    }
}

// =========================================================================
// Kernel 2 (main): persistent 512x1024, launch_bounds(1024,4) -> 64-VGPR
// cap, 73 KB LDS -> 2 blocks/CU = 32 waves/CU. Quarter-user jobs, rolled
// nt. V pass uses MFMA LINEARITY: (item+opin)@Wv = item@Wv + opin@Wv
// (chained MFMAs, no f32 add/repack). BF16 template: gathers read pre-cast
// bf16 tables (half the bytes, zero cvt in loop). tanh in exp2 form with
// pre-scaled biases. atomicAdd into prep-zeroed out.
// =========================================================================
template<int BF16>
__global__ __launch_bounds__(1024, 4) void finerec_main(
    const float* __restrict__ item_table, const float* __restrict__ opin_table,
    const int* __restrict__ item_seqs, const int* __restrict__ opin_seqs,
    const float* __restrict__ q_ws, const float* __restrict__ bkz_ws,
    const float* __restrict__ bvz_ws, const short* __restrict__ wf_ws,
    const short* __restrict__ itb, const short* __restrict__ opb,
    float* __restrict__ out, int U, int L)
{
    __shared__ __align__(16) short wlds[32768];   // Wk + Wv frag chunks, XOR-swizzled
    __shared__ float q_lds[16 * 128];
    __shared__ float bkz_lds[128], bvz_lds[128];

    const int tid = threadIdx.x;
    const int wv = tid >> 6, lane = tid & 63, l15 = lane & 15, quad = lane >> 4;

    const bf16x8* wsrc = (const bf16x8*)wf_ws;
    bf16x8* wldsv = (bf16x8*)wlds;
#pragma unroll
    for (int i = 0; i < 4; ++i)
        wldsv[i * 1024 + tid] = wsrc[i * 1024 + tid];
    if (tid < 128)      bkz_lds[tid]       = bkz_ws[tid];
    else if (tid < 256) bvz_lds[tid - 128] = bvz_ws[tid - 128];
    __syncthreads();   // the ONLY block barrier

    const int nwaves = gridDim.x * 16;
    const int njobs  = 4 * U;

#pragma unroll 1
    for (int job = blockIdx.x * 16 + wv; job < njobs; job += nwaves) {
        const int u  = job >> 2;
        const int rb = (job & 3) * 16;   // rows rb..rb+15 of user u

        int vi = 0, vo = 0;
        if (lane < 16 && rb + lane < L) {
            vi = item_seqs[u * L + rb + lane];
            vo = opin_seqs[u * L + rb + lane];
        }
        const unsigned long long mb = __ballot(vi > 0);

        q_lds[wv * 128 + lane]      = q_ws[u * 128 + lane];
        q_lds[wv * 128 + 64 + lane] = q_ws[u * 128 + 64 + lane];

        // ---- gather item rows -> A-frags ----
        const int idx = __shfl(vi, l15);
        bf16x8 ai[4];
        if (BF16) {
            const bf16x8* pb = (const bf16x8*)itb + (size_t)idx * 16 + quad;
#pragma unroll
            for (int ks = 0; ks < 4; ++ks) ai[ks] = pb[ks * 4];
        } else {
            const float* p = item_table + (size_t)idx * 128 + quad * 8;
#pragma unroll
            for (int ks = 0; ks < 4; ++ks)
                ai[ks] = pack2(*(const float4*)(p + ks * 32), *(const float4*)(p + ks * 32 + 4));
        }

        // ---- K pass (attr folded into bkz); rolled nt ----
        float w[4] = {0, 0, 0, 0};
#pragma unroll 1
        for (int nt = 0; nt < 8; ++nt) {
            const int n = nt * 16 + l15;
            f32x4 c = {0, 0, 0, 0};
#pragma unroll
            for (int ks = 0; ks < 4; ++ks)
                c = MFMA16(ai[ks], wldsv[(n << 4) + ((ks * 4 + quad) ^ (n & 15))], c);
            const float qv  = q_lds[wv * 128 + n];
            const float bkz = bkz_lds[n];
#pragma unroll
            for (int r = 0; r < 4; ++r)
                w[r] = fmaf(qv, tanh_z(fmaf(c[r], S_2LOG2E, bkz)), w[r]);
        }
        // ---- w: reduce over 16 cols within quad + padding mask ----
#pragma unroll
        for (int r = 0; r < 4; ++r) {
            float t = w[r];
            t += __shfl_xor(t, 1); t += __shfl_xor(t, 2);
            t += __shfl_xor(t, 4); t += __shfl_xor(t, 8);
            w[r] = ((mb >> (quad * 4 + r)) & 1ull) ? t : 0.0f;
        }
        // ---- gather opin rows -> second A-frags (linearity: no add/repack) ----
        const int od = __shfl(vo, l15);
        bf16x8 ao[4];
        if (BF16) {
            const bf16x8* pb = (const bf16x8*)opb + (size_t)od * 16 + quad;
#pragma unroll
            for (int ks = 0; ks < 4; ++ks) ao[ks] = pb[ks * 4];
        } else {
            const float* p = opin_table + (size_t)od * 128 + quad * 8;
#pragma unroll
            for (int ks = 0; ks < 4; ++ks)
                ao[ks] = pack2(*(const float4*)(p + ks * 32), *(const float4*)(p + ks * 32 + 4));
        }
        // ---- V pass: c = (item + opin) @ Wv via chained MFMAs ----
        float s0 = 0.0f, s1 = 0.0f;
#pragma unroll 1
        for (int nt = 0; nt < 8; ++nt) {
            const int n = nt * 16 + l15;
            f32x4 c = {0, 0, 0, 0};
#pragma unroll
            for (int ks = 0; ks < 4; ++ks) {
                bf16x8 wf = wldsv[2048 + (n << 4) + ((ks * 4 + quad) ^ (n & 15))];
                c = MFMA16(ai[ks], wf, c);
                c = MFMA16(ao[ks], wf, c);
            }
            const float bvz = bvz_lds[n];
            float acc = 0.0f;
#pragma unroll
            for (int r = 0; r < 4; ++r)
                acc = fmaf(w[r], tanh_z(fmaf(c[r], S_2LOG2E, bvz)), acc);
            acc += __shfl_xor(acc, 16);
            acc += __shfl_xor(acc, 32);
            const bool mine = (quad == (nt >> 1));
            s0 += (mine && !(nt & 1)) ? acc : 0.0f;
            s1 += (mine &&  (nt & 1)) ? acc : 0.0f;
        }
        atomicAdd(out + u * 128 + quad * 32 + l15, s0);
        atomicAdd(out + u * 128 + quad * 32 + 16 + l15, s1);
    }
}

extern "C" void kernel_launch(void* const* d_in, const int* in_sizes, int n_in,
                              void* d_out, int out_size, void* d_ws, size_t ws_size,
                              hipStream_t stream) {
    const float* item_table = (const float*)d_in[0];
    const float* opin_table = (const float*)d_in[1];
    const float* user_emb   = (const float*)d_in[2];
    const float* attr       = (const float*)d_in[3];
    const float* Wq = (const float*)d_in[4];
    const float* bq = (const float*)d_in[5];
    const float* Wk = (const float*)d_in[6];
    const float* bk = (const float*)d_in[7];
    const float* Wv = (const float*)d_in[8];
    const float* bv = (const float*)d_in[9];
    const int* item_seqs = (const int*)d_in[10];
    const int* opin_seqs = (const int*)d_in[11];
    float* out = (float*)d_out;

    const int U = in_sizes[2] / 128;        // 10000
    const int L = in_sizes[10] / U;         // 50
    const int n_item = in_sizes[0] / 128;   // 50000
    const int n_opi  = in_sizes[1] / 128;   // 5000

    // ---- ws layout ----
    char* w = (char*)d_ws;
    float* q_ws   = (float*)w;               w += (size_t)U * 128 * 4;
    float* bkz_ws = (float*)w;               w += 512;
    float* bvz_ws = (float*)w;               w += 512;
    short* wf_ws  = (short*)w;               w += 4096 * 16;
    short* itb    = (short*)w;               w += (size_t)n_item * 128 * 2;
    short* opb    = (short*)w;               w += (size_t)n_opi * 128 * 2;
    const size_t need = (size_t)(w - (char*)d_ws);
    const int use_bf16 = (ws_size >= need) ? 1 : 0;

    const int qb = (U + 63) / 64;
    const int prep_grid = qb + 49 + (use_bf16 ? 224 : 0);
    finerec_prep<<<prep_grid, 256, 0, stream>>>(
        user_emb, attr, Wq, bq, Wk, bk, Wv, bv, item_table, opin_table,
        q_ws, bkz_ws, bvz_ws, wf_ws, itb, opb, out, U, n_item, n_opi, qb);

    if (use_bf16)
        finerec_main<1><<<512, 1024, 0, stream>>>(
            item_table, opin_table, item_seqs, opin_seqs,
            q_ws, bkz_ws, bvz_ws, wf_ws, itb, opb, out, U, L);
    else
        finerec_main<0><<<512, 1024, 0, stream>>>(
            item_table, opin_table, item_seqs, opin_seqs,
            q_ws, bkz_ws, bvz_ws, wf_ws, itb, opb, out, U, L);
}